// Round 1
// baseline (649.948 us; speedup 1.0000x reference)
//
#include <hip/hip_runtime.h>

#define TPB 256

// ---------------- CSR build ----------------

__global__ void zero_int_kernel(int* __restrict__ p, int n) {
  int i = blockIdx.x * TPB + threadIdx.x;
  if (i < n) p[i] = 0;
}

__global__ void degree_kernel(const int* __restrict__ src, const int* __restrict__ dst,
                              int* __restrict__ deg_out, int* __restrict__ deg_in, int e) {
  int i = blockIdx.x * TPB + threadIdx.x;
  if (i < e) {
    atomicAdd(&deg_out[src[i]], 1);
    atomicAdd(&deg_in[dst[i]], 1);
  }
}

__global__ void invsqrt_kernel(const int* __restrict__ deg_out, const int* __restrict__ deg_in,
                               float* __restrict__ inv_out, float* __restrict__ inv_in, int n) {
  int i = blockIdx.x * TPB + threadIdx.x;
  if (i < n) {
    inv_out[i] = rsqrtf(fmaxf((float)deg_out[i], 1.0f));
    inv_in[i]  = rsqrtf(fmaxf((float)deg_in[i], 1.0f));
  }
}

// exclusive scan of deg_in -> row_ptr (and cursor copy), 1024 elems per block
__global__ void scan_p1(const int* __restrict__ deg, int n, int* __restrict__ bsums) {
  int b = blockIdx.x, t = threadIdx.x;
  int base = b * 1024 + t * 4;
  int s = 0;
  #pragma unroll
  for (int i = 0; i < 4; i++) { int idx = base + i; if (idx < n) s += deg[idx]; }
  __shared__ int lds[TPB];
  lds[t] = s; __syncthreads();
  for (int off = TPB / 2; off > 0; off >>= 1) {
    if (t < off) lds[t] += lds[t + off];
    __syncthreads();
  }
  if (t == 0) bsums[b] = lds[0];
}

__global__ void scan_p2(int* __restrict__ bsums, int nb, int* __restrict__ row_ptr, int n) {
  if (threadIdx.x == 0 && blockIdx.x == 0) {
    int acc = 0;
    for (int i = 0; i < nb; i++) { int v = bsums[i]; bsums[i] = acc; acc += v; }
    row_ptr[n] = acc;
  }
}

__global__ void scan_p3(const int* __restrict__ deg, int n, const int* __restrict__ bsums,
                        int* __restrict__ row_ptr, int* __restrict__ cursor) {
  int b = blockIdx.x, t = threadIdx.x;
  int base = b * 1024 + t * 4;
  int v[4]; int s = 0;
  #pragma unroll
  for (int i = 0; i < 4; i++) { int idx = base + i; v[i] = (idx < n) ? deg[idx] : 0; s += v[i]; }
  __shared__ int lds[TPB];
  lds[t] = s; __syncthreads();
  for (int off = 1; off < TPB; off <<= 1) {
    int add = (t >= off) ? lds[t - off] : 0;
    __syncthreads();
    lds[t] += add;
    __syncthreads();
  }
  int run = bsums[b] + ((t == 0) ? 0 : lds[t - 1]);
  #pragma unroll
  for (int i = 0; i < 4; i++) {
    int idx = base + i;
    if (idx < n) { row_ptr[idx] = run; cursor[idx] = run; run += v[i]; }
  }
}

__global__ void csr_fill(const int* __restrict__ src, const int* __restrict__ dst, int e,
                         int* __restrict__ cursor, int* __restrict__ col) {
  int i = blockIdx.x * TPB + threadIdx.x;
  if (i < e) {
    int p = atomicAdd(&cursor[dst[i]], 1);
    col[p] = src[i];
  }
}

// ---------------- SpMM: agg[row,:] = sum_{c in col(row)} x[c,:] * inv_out[c] ----------------
// one wave per dst row: 16 lanes x float4 features, 4 edges in flight per wave
__global__ __launch_bounds__(256) void spmm_kernel(const float* __restrict__ x, int ldx,
    const int* __restrict__ row_ptr, const int* __restrict__ col,
    const float* __restrict__ inv_out, float* __restrict__ agg, int n) {
  int wid = (blockIdx.x * TPB + threadIdx.x) >> 6;
  if (wid >= n) return;
  int lane = threadIdx.x & 63;
  int g = lane >> 4;            // edge slot 0..3
  int f4 = (lane & 15) << 2;    // feature offset
  int s = row_ptr[wid], e = row_ptr[wid + 1];
  float ax = 0.f, ay = 0.f, az = 0.f, aw = 0.f;
  for (int i = s + g; i < e; i += 4) {
    int c = col[i];
    float wgt = inv_out[c];
    const float4 xv = *(const float4*)&x[(size_t)c * ldx + f4];
    ax = fmaf(xv.x, wgt, ax);
    ay = fmaf(xv.y, wgt, ay);
    az = fmaf(xv.z, wgt, az);
    aw = fmaf(xv.w, wgt, aw);
  }
  // reduce across the 4 edge groups (lanes xor 16, 32)
  ax += __shfl_xor(ax, 16); ax += __shfl_xor(ax, 32);
  ay += __shfl_xor(ay, 16); ay += __shfl_xor(ay, 32);
  az += __shfl_xor(az, 16); az += __shfl_xor(az, 32);
  aw += __shfl_xor(aw, 16); aw += __shfl_xor(aw, 32);
  if (g == 0) {
    float4 r = {ax, ay, az, aw};
    *(float4*)&agg[(size_t)wid * 64 + f4] = r;
  }
}

// ---------------- GEMM + bias + ReLU + strided store + row-sum pool ----------------
// block: 64 rows x 64 cols; thread: 4x4 register tile
__global__ __launch_bounds__(256) void gemm_relu_pool(
    const float* __restrict__ agg, const float* __restrict__ inv_in,
    const float* __restrict__ W, const float* __restrict__ bias,
    float* __restrict__ out_cat, float* __restrict__ out_pool, int n) {
  __shared__ float sW[64 * 64];
  __shared__ float sXT[64][68];   // transposed, stride 68 keeps 16B alignment + spreads banks
  int t = threadIdx.x;
  int row0 = blockIdx.x * 64;
  for (int i = t; i < 4096; i += TPB) sW[i] = W[i];
  for (int i = t; i < 4096; i += TPB) {
    int r = i >> 6, f = i & 63;
    int row = row0 + r;
    sXT[f][r] = (row < n) ? agg[(size_t)row * 64 + f] * inv_in[row] : 0.f;
  }
  __syncthreads();
  int tj = t & 15, tr = t >> 4;
  int j4 = tj << 2, r4 = tr << 2;
  const float4 bv = *(const float4*)&bias[j4];
  float4 a0 = bv, a1 = bv, a2 = bv, a3 = bv;
  #pragma unroll 8
  for (int f = 0; f < 64; f++) {
    float4 w  = *(const float4*)&sW[f * 64 + j4];
    float4 xv = *(const float4*)&sXT[f][r4];
    a0.x = fmaf(xv.x, w.x, a0.x); a0.y = fmaf(xv.x, w.y, a0.y);
    a0.z = fmaf(xv.x, w.z, a0.z); a0.w = fmaf(xv.x, w.w, a0.w);
    a1.x = fmaf(xv.y, w.x, a1.x); a1.y = fmaf(xv.y, w.y, a1.y);
    a1.z = fmaf(xv.y, w.z, a1.z); a1.w = fmaf(xv.y, w.w, a1.w);
    a2.x = fmaf(xv.z, w.x, a2.x); a2.y = fmaf(xv.z, w.y, a2.y);
    a2.z = fmaf(xv.z, w.z, a2.z); a2.w = fmaf(xv.z, w.w, a2.w);
    a3.x = fmaf(xv.w, w.x, a3.x); a3.y = fmaf(xv.w, w.y, a3.y);
    a3.z = fmaf(xv.w, w.z, a3.z); a3.w = fmaf(xv.w, w.w, a3.w);
  }
  float4 accs[4] = {a0, a1, a2, a3};
  #pragma unroll
  for (int ri = 0; ri < 4; ri++) {
    int row = row0 + r4 + ri;
    if (row < n) {
      float4 h = accs[ri];
      h.x = fmaxf(h.x, 0.f); h.y = fmaxf(h.y, 0.f);
      h.z = fmaxf(h.z, 0.f); h.w = fmaxf(h.w, 0.f);
      *(float4*)&out_cat[(size_t)row * 192 + j4] = h;
      float part = h.x + h.y + h.z + h.w;
      part += __shfl_xor(part, 1);
      part += __shfl_xor(part, 2);
      part += __shfl_xor(part, 4);
      part += __shfl_xor(part, 8);
      if (tj == 0) out_pool[row] = part;
    }
  }
}

// ---------------- launch ----------------

extern "C" void kernel_launch(void* const* d_in, const int* in_sizes, int n_in,
                              void* d_out, int out_size, void* d_ws, size_t ws_size,
                              hipStream_t stream) {
  const float* node_feat = (const float*)d_in[0];
  const int* src = (const int*)d_in[1];
  const int* dst = (const int*)d_in[2];
  // d_in[3] = graph_len (unused, == n)
  const float* Ws[3] = {(const float*)d_in[4], (const float*)d_in[6], (const float*)d_in[8]};
  const float* bs[3] = {(const float*)d_in[5], (const float*)d_in[7], (const float*)d_in[9]};
  float* out = (float*)d_out;
  int n = in_sizes[0] / 64;
  int e = in_sizes[1];

  char* p = (char*)d_ws;
  float* agg = (float*)p;     p += (size_t)n * 64 * sizeof(float);
  float* inv_out = (float*)p; p += (size_t)n * sizeof(float);
  float* inv_in = (float*)p;  p += (size_t)n * sizeof(float);
  int* deg = (int*)p;         p += (size_t)2 * n * sizeof(int);   // deg_out | deg_in
  int* row_ptr = (int*)p;     p += ((size_t)n + 4) * sizeof(int);
  int* cursor = (int*)p;      p += (size_t)n * sizeof(int);
  int* bsums = (int*)p;       p += 512;
  int* col = (int*)p;         p += (size_t)e * sizeof(int);

  int* deg_out = deg;
  int* deg_in = deg + n;
  int nb = (n + 1023) / 1024;

  zero_int_kernel<<<(2 * n + TPB - 1) / TPB, TPB, 0, stream>>>(deg, 2 * n);
  degree_kernel<<<(e + TPB - 1) / TPB, TPB, 0, stream>>>(src, dst, deg_out, deg_in, e);
  invsqrt_kernel<<<(n + TPB - 1) / TPB, TPB, 0, stream>>>(deg_out, deg_in, inv_out, inv_in, n);
  scan_p1<<<nb, TPB, 0, stream>>>(deg_in, n, bsums);
  scan_p2<<<1, 64, 0, stream>>>(bsums, nb, row_ptr, n);
  scan_p3<<<nb, TPB, 0, stream>>>(deg_in, n, bsums, row_ptr, cursor);
  csr_fill<<<(e + TPB - 1) / TPB, TPB, 0, stream>>>(src, dst, e, cursor, col);

  float* cat_base = out + (size_t)3 * n;
  for (int layer = 0; layer < 3; layer++) {
    const float* x; int ldx;
    if (layer == 0) { x = node_feat; ldx = 64; }
    else { x = cat_base + (size_t)(layer - 1) * 64; ldx = 192; }
    spmm_kernel<<<(n + 3) / 4, TPB, 0, stream>>>(x, ldx, row_ptr, col, inv_out, agg, n);
    gemm_relu_pool<<<(n + 63) / 64, TPB, 0, stream>>>(agg, inv_in, Ws[layer], bs[layer],
        cat_base + (size_t)layer * 64, out + (size_t)layer * n, n);
  }
}